// Round 2
// baseline (248.636 us; speedup 1.0000x reference)
//
#include <hip/hip_runtime.h>

#define NN 40000      // nodes
#define NE 400000     // edges
#define IC 64         // in channels
#define HC 16         // hidden
#define NR 90         // relations
#define NB 30         // bases
#define NC 8          // classes

// ---------------- weight collapse: W[r] = sum_b comp[r,b] * basis[b] ----------------
__global__ void k_weights(const float* __restrict__ comp1, const float* __restrict__ basis1,
                          const float* __restrict__ comp2, const float* __restrict__ basis2,
                          float* __restrict__ W1, float* __restrict__ W2) {
    const int n1 = NR * IC * HC;          // 92160
    const int n2 = NR * HC * NC;          // 11520
    int t = blockIdx.x * blockDim.x + threadIdx.x;
    if (t < n1) {
        int r = t / (IC * HC);
        int io = t - r * (IC * HC);
        float acc = 0.f;
#pragma unroll
        for (int b = 0; b < NB; ++b)
            acc += comp1[r * NB + b] * basis1[b * (IC * HC) + io];
        W1[t] = acc;
    } else if (t < n1 + n2) {
        int t2 = t - n1;
        int r = t2 / (HC * NC);
        int io = t2 - r * (HC * NC);
        float acc = 0.f;
#pragma unroll
        for (int b = 0; b < NB; ++b)
            acc += comp2[r * NB + b] * basis2[b * (HC * NC) + io];
        W2[t2] = acc;
    }
}

// ---------------- per-(dst, rel) edge counts ----------------
__global__ void k_count(const int* __restrict__ dst, const int* __restrict__ et,
                        int* __restrict__ cnt) {
    int e = blockIdx.x * blockDim.x + threadIdx.x;
    if (e < NE) atomicAdd(&cnt[dst[e] * NR + et[e]], 1);
}

// ---------------- per-edge norm = 1/max(cnt,1) ----------------
__global__ void k_norm(const int* __restrict__ dst, const int* __restrict__ et,
                       const int* __restrict__ cnt, float* __restrict__ norm) {
    int e = blockIdx.x * blockDim.x + threadIdx.x;
    if (e < NE) {
        int c = cnt[dst[e] * NR + et[e]];
        norm[e] = 1.0f / (float)(c > 1 ? c : 1);
    }
}

// ---------------- layer-1 edge messages: agg1[dst] += norm * x[src] @ W1[et] ----------------
__global__ void k_msg1(const int* __restrict__ src, const int* __restrict__ dst,
                       const int* __restrict__ et, const float* __restrict__ norm,
                       const float* __restrict__ x, const float* __restrict__ W1,
                       float* __restrict__ agg1) {
    int t = blockIdx.x * blockDim.x + threadIdx.x;
    if (t >= NE * HC) return;
    int e = t >> 4;        // /HC
    int o = t & (HC - 1);
    int s = src[e], d = dst[e], r = et[e];
    const float* xr = x + s * IC;
    const float* w = W1 + r * (IC * HC) + o;
    float acc = 0.f;
#pragma unroll
    for (int i = 0; i < IC; ++i)
        acc += xr[i] * w[i * HC];
    atomicAdd(&agg1[d * HC + o], acc * norm[e]);
}

// ---------------- layer-1 node update: h = relu(agg1 + x@root1 + bias1) ----------------
__global__ void k_node1(const float* __restrict__ x, const float* __restrict__ root1,
                        const float* __restrict__ bias1, const float* __restrict__ agg1,
                        float* __restrict__ h) {
    int t = blockIdx.x * blockDim.x + threadIdx.x;
    if (t >= NN * HC) return;
    int n = t >> 4;
    int o = t & (HC - 1);
    const float* xr = x + n * IC;
    float acc = agg1[t] + bias1[o];
#pragma unroll
    for (int i = 0; i < IC; ++i)
        acc += xr[i] * root1[i * HC + o];
    h[t] = fmaxf(acc, 0.f);
}

// ---------------- layer-2 edge messages: agg2[dst] += norm * h[src] @ W2[et] ----------------
__global__ void k_msg2(const int* __restrict__ src, const int* __restrict__ dst,
                       const int* __restrict__ et, const float* __restrict__ norm,
                       const float* __restrict__ h, const float* __restrict__ W2,
                       float* __restrict__ agg2) {
    int t = blockIdx.x * blockDim.x + threadIdx.x;
    if (t >= NE * NC) return;
    int e = t >> 3;        // /NC
    int o = t & (NC - 1);
    int s = src[e], d = dst[e], r = et[e];
    const float* hr = h + s * HC;
    const float* w = W2 + r * (HC * NC) + o;
    float acc = 0.f;
#pragma unroll
    for (int i = 0; i < HC; ++i)
        acc += hr[i] * w[i * NC];
    atomicAdd(&agg2[d * NC + o], acc * norm[e]);
}

// ---------------- layer-2 node update + log_softmax ----------------
__global__ void k_node2(const float* __restrict__ h, const float* __restrict__ root2,
                        const float* __restrict__ bias2, const float* __restrict__ agg2,
                        float* __restrict__ out) {
    int n = blockIdx.x * blockDim.x + threadIdx.x;
    if (n >= NN) return;
    const float* hr = h + n * HC;
    float v[NC];
#pragma unroll
    for (int o = 0; o < NC; ++o) {
        float acc = agg2[n * NC + o] + bias2[o];
#pragma unroll
        for (int i = 0; i < HC; ++i)
            acc += hr[i] * root2[i * NC + o];
        v[o] = acc;
    }
    float m = v[0];
#pragma unroll
    for (int o = 1; o < NC; ++o) m = fmaxf(m, v[o]);
    float s = 0.f;
#pragma unroll
    for (int o = 0; o < NC; ++o) s += expf(v[o] - m);
    float lse = m + logf(s);
#pragma unroll
    for (int o = 0; o < NC; ++o) out[n * NC + o] = v[o] - lse;
}

extern "C" void kernel_launch(void* const* d_in, const int* in_sizes, int n_in,
                              void* d_out, int out_size, void* d_ws, size_t ws_size,
                              hipStream_t stream) {
    const float* x      = (const float*)d_in[0];
    const int*   eidx   = (const int*)d_in[1];     // [2, NE]
    const int*   etype  = (const int*)d_in[2];
    const float* comp1  = (const float*)d_in[3];
    const float* basis1 = (const float*)d_in[4];
    const float* root1  = (const float*)d_in[5];
    const float* bias1  = (const float*)d_in[6];
    const float* comp2  = (const float*)d_in[7];
    const float* basis2 = (const float*)d_in[8];
    const float* root2  = (const float*)d_in[9];
    const float* bias2  = (const float*)d_in[10];
    float* out = (float*)d_out;

    const int* src = eidx;
    const int* dst = eidx + NE;

    // workspace layout (bytes, 256-aligned)
    char* ws = (char*)d_ws;
    size_t off = 0;
    auto alloc = [&](size_t bytes) {
        char* p = ws + off;
        off = (off + bytes + 255) & ~(size_t)255;
        return p;
    };
    float* W1   = (float*)alloc(NR * IC * HC * sizeof(float));   // 368640
    float* W2   = (float*)alloc(NR * HC * NC * sizeof(float));   // 46080
    int*   cnt  = (int*)  alloc((size_t)NN * NR * sizeof(int));  // 14.4 MB
    float* nrm  = (float*)alloc(NE * sizeof(float));             // 1.6 MB
    float* agg1 = (float*)alloc(NN * HC * sizeof(float));        // 2.56 MB
    float* h    = (float*)alloc(NN * HC * sizeof(float));        // 2.56 MB
    float* agg2 = (float*)alloc(NN * NC * sizeof(float));        // 1.28 MB

    // zero the accumulators (ws is poisoned to 0xAA before every call)
    hipMemsetAsync(cnt,  0, (size_t)NN * NR * sizeof(int), stream);
    hipMemsetAsync(agg1, 0, NN * HC * sizeof(float), stream);
    hipMemsetAsync(agg2, 0, NN * NC * sizeof(float), stream);

    const int B = 256;
    int nW = NR * IC * HC + NR * HC * NC;
    k_weights<<<(nW + B - 1) / B, B, 0, stream>>>(comp1, basis1, comp2, basis2, W1, W2);
    k_count  <<<(NE + B - 1) / B, B, 0, stream>>>(dst, etype, cnt);
    k_norm   <<<(NE + B - 1) / B, B, 0, stream>>>(dst, etype, cnt, nrm);
    k_msg1   <<<(NE * HC + B - 1) / B, B, 0, stream>>>(src, dst, etype, nrm, x, W1, agg1);
    k_node1  <<<(NN * HC + B - 1) / B, B, 0, stream>>>(x, root1, bias1, agg1, h);
    k_msg2   <<<(NE * NC + B - 1) / B, B, 0, stream>>>(src, dst, etype, nrm, h, W2, agg2);
    k_node2  <<<(NN + B - 1) / B, B, 0, stream>>>(h, root2, bias2, agg2, out);
}